// Round 1
// baseline (858.219 us; speedup 1.0000x reference)
//
#include <hip/hip_runtime.h>
#include <hip/hip_bf16.h>

// B=2, S=128, H=12, DH=64, HID=768
// scores(b,h,i,j) = dot64(q[b,h,i]+ra, k[b,h,j]+rb)/8 + mask
//   ra = ip_a[r, 64c..], rb = ip_b[r, 64c..], t = h*16384+i*128+j, r=t/12, c=t%12
//   ip = inference_path @ Wip  (the 77 GFLOP GEMM, done in bf16 MFMA, never materialized)

typedef __attribute__((ext_vector_type(8))) __bf16 bf16x8;
typedef __attribute__((ext_vector_type(16))) float f32x16;

// ---------------- kernel A: q/k/v/pv projections (fp32, 32x32 tiles) ----------------
__global__ __launch_bounds__(256)
void proj_kernel(const float* __restrict__ hs,
                 const float* __restrict__ Wq, const float* __restrict__ bq,
                 const float* __restrict__ Wk, const float* __restrict__ bk,
                 const float* __restrict__ Wv, const float* __restrict__ bv,
                 const float* __restrict__ Wpv, const float* __restrict__ bpv,
                 float* __restrict__ qkv) {
  const int n0 = blockIdx.x * 32;   // 0..2367 (74 tiles)
  const int m0 = blockIdx.y * 32;   // 0..255  (8 tiles)
  const float* W; const float* bias; int noff, ldw;
  if (n0 < 768)       { W = Wq;  bias = bq;  noff = n0;        ldw = 768; }
  else if (n0 < 1536) { W = Wk;  bias = bk;  noff = n0 - 768;  ldw = 768; }
  else if (n0 < 2304) { W = Wv;  bias = bv;  noff = n0 - 1536; ldw = 768; }
  else                { W = Wpv; bias = bpv; noff = n0 - 2304; ldw = 64; }
  __shared__ float As[32][17];
  __shared__ float Bs[16][33];
  const int tid = threadIdx.x;
  const int tx = tid & 15, ty = tid >> 4;
  float acc[2][2] = {};
  for (int k0 = 0; k0 < 768; k0 += 16) {
    {
      int e = tid, row = e >> 4, kk = e & 15;
      As[row][kk] = hs[(m0 + row) * 768 + k0 + kk];
      e = tid + 256; row = e >> 4; kk = e & 15;
      As[row][kk] = hs[(m0 + row) * 768 + k0 + kk];
      e = tid; int kb = e >> 5, col = e & 31;
      Bs[kb][col] = W[(k0 + kb) * ldw + noff + col];
      e = tid + 256; kb = e >> 5; col = e & 31;
      Bs[kb][col] = W[(k0 + kb) * ldw + noff + col];
    }
    __syncthreads();
#pragma unroll
    for (int kk = 0; kk < 16; kk++) {
      float a0 = As[ty * 2][kk], a1 = As[ty * 2 + 1][kk];
      float b0 = Bs[kk][tx * 2], b1 = Bs[kk][tx * 2 + 1];
      acc[0][0] += a0 * b0; acc[0][1] += a0 * b1;
      acc[1][0] += a1 * b0; acc[1][1] += a1 * b1;
    }
    __syncthreads();
  }
#pragma unroll
  for (int p = 0; p < 2; p++)
#pragma unroll
    for (int q = 0; q < 2; q++)
      qkv[(size_t)(m0 + ty * 2 + p) * 2368 + n0 + tx * 2 + q] =
          acc[p][q] + bias[noff + tx * 2 + q];
}

// ---------------- kernel T: Wip [768][1536] fp32 -> WipT [1536][768] bf16 ----------------
__global__ __launch_bounds__(256)
void wipt_kernel(const float* __restrict__ Wip, __bf16* __restrict__ WipT) {
  __shared__ float tbuf[32][33];
  const int n0 = blockIdx.x * 32;   // 48 tiles
  const int k0 = blockIdx.y * 32;   // 24 tiles
  const int tx = threadIdx.x & 31, ty = threadIdx.x >> 5;  // 256 thr: ty 0..7
#pragma unroll
  for (int i = 0; i < 4; i++) {
    int k = ty + i * 8;
    tbuf[k][tx] = Wip[(size_t)(k0 + k) * 1536 + n0 + tx];
  }
  __syncthreads();
#pragma unroll
  for (int i = 0; i < 4; i++) {
    int n = ty + i * 8;
    WipT[(size_t)(n0 + n) * 768 + k0 + tx] = (__bf16)tbuf[tx][n];
  }
}

// ---------------- kernel B: fused ip-GEMM + score reduction ----------------
// grid 512 blocks x 256 thr. Block: batch b, rows r0..r0+63 (A resident in LDS, bf16).
// waves (aw,wb): rows 32aw..+31, d-range [32wb,32wb+32). acc0=ra tile, acc1=rb tile.
extern __shared__ char smem_raw[];

__global__ __launch_bounds__(256, 1)
void score_kernel(const float* __restrict__ infp,
                  const __bf16* __restrict__ WipT,
                  const float* __restrict__ qkv,
                  float* __restrict__ scores) {
  __bf16* As = (__bf16*)smem_raw;                    // [64][776] bf16 = 99328 B
  __bf16* Bs = (__bf16*)(smem_raw + 64 * 776 * 2);   // [2][128][72] bf16 = 36864 B
  const int tid = threadIdx.x;
  const int lane = tid & 63;
  const int wv = tid >> 6;
  const int aw = wv >> 1;        // row half
  const int wb = wv & 1;         // d half
  const int ml = lane & 31;
  const int kh = lane >> 5;
  const int blk = blockIdx.x;
  const int b = blk >> 8;
  const int r0 = (blk & 255) << 6;

  // ---- stage A: 64 rows x 768 fp32 -> bf16 in LDS (read once from HBM)
  const float4* A4 = (const float4*)(infp + (size_t)(b * 16384 + r0) * 768);
#pragma unroll 4
  for (int it = 0; it < 48; it++) {
    int f = it * 256 + tid;          // 0..12287 float4s
    int row = f / 192;
    int k4 = f - row * 192;
    float4 v = A4[f];
    union { __bf16 h[4]; uint2 u; } pk;
    pk.h[0] = (__bf16)v.x; pk.h[1] = (__bf16)v.y;
    pk.h[2] = (__bf16)v.z; pk.h[3] = (__bf16)v.w;
    *(uint2*)(As + row * 776 + k4 * 4) = pk.u;
  }
  __syncthreads();

  uint4 breg[4];
  auto loadB = [&](int c, int kc) {
#pragma unroll
    for (int p = 0; p < 4; p++) {
      int g = p * 256 + tid;
      int nn = g >> 3, k8 = g & 7;
      int ng = (nn < 64) ? (64 * c + nn) : (704 + 64 * c + nn);  // ra cols / rb cols (+768)
      breg[p] = *(const uint4*)(WipT + (size_t)ng * 768 + kc * 64 + k8 * 8);
    }
  };
  auto storeB = [&](int buf) {
#pragma unroll
    for (int p = 0; p < 4; p++) {
      int g = p * 256 + tid;
      int nn = g >> 3, k8 = g & 7;
      *(uint4*)(Bs + buf * 9216 + nn * 72 + k8 * 8) = breg[p];
    }
  };

  for (int c = 0; c < 12; c++) {
    f32x16 acc0, acc1;
#pragma unroll
    for (int z = 0; z < 16; z++) { acc0[z] = 0.f; acc1[z] = 0.f; }

    loadB(c, 0);
    storeB(0);
    __syncthreads();
    for (int kc = 0; kc < 12; kc++) {
      if (kc < 11) loadB(c, kc + 1);            // prefetch next chunk into regs
      const __bf16* Ab  = As + (aw * 32 + ml) * 776 + kc * 64 + kh * 8;
      const __bf16* Bra = Bs + (kc & 1) * 9216 + (wb * 32 + ml) * 72 + kh * 8;
      const __bf16* Brb = Bra + 64 * 72;
#pragma unroll
      for (int ks = 0; ks < 4; ks++) {
        bf16x8 af = *(const bf16x8*)(Ab + ks * 16);
        bf16x8 b0 = *(const bf16x8*)(Bra + ks * 16);
        bf16x8 b1 = *(const bf16x8*)(Brb + ks * 16);
        acc0 = __builtin_amdgcn_mfma_f32_32x32x16_bf16(af, b0, acc0, 0, 0, 0);
        acc1 = __builtin_amdgcn_mfma_f32_32x32x16_bf16(af, b1, acc1, 0, 0, 0);
      }
      __syncthreads();
      if (kc < 11) storeB((kc + 1) & 1);
      __syncthreads();
    }

    // ---- epilogue: (q+ra)·(k+rb) partial over this wave's 32 d's, atomic into scores
#pragma unroll
    for (int reg = 0; reg < 16; reg++) {
      int mrow = (reg & 3) + ((reg >> 2) << 3) + (kh << 2);   // C/D row mapping 32x32
      int m = aw * 32 + mrow;
      int t = 12 * (r0 + m) + c;
      int hh = t >> 14;
      int ii = (t >> 7) & 127;
      int jj = t & 127;
      int d = wb * 32 + ml;
      float qv = qkv[(size_t)((b << 7) + ii) * 2368 + (hh << 6) + d];
      float kv = qkv[(size_t)((b << 7) + jj) * 2368 + 768 + (hh << 6) + d];
      float p = (qv + acc0[reg]) * (kv + acc1[reg]);
      p += __shfl_xor(p, 16);
      p += __shfl_xor(p, 8);
      p += __shfl_xor(p, 4);
      p += __shfl_xor(p, 2);
      p += __shfl_xor(p, 1);
      if (ml == 0)
        atomicAdd(scores + (size_t)((b * 12 + hh) * 128 + ii) * 128 + jj, p);
    }
  }
}

// ---------------- kernel C: softmax + probs@v (+ parse path as head 12) ----------------
__global__ __launch_bounds__(128)
void attn_kernel(const float* __restrict__ scores, const float* __restrict__ qkv,
                 const float* __restrict__ mask, const float* __restrict__ span,
                 float* __restrict__ ctx) {
  const int h = blockIdx.x;   // 0..12 (12 = parse path)
  const int i = blockIdx.y;   // 0..127
  const int b = blockIdx.z;   // 0..1
  const int tid = threadIdx.x;
  __shared__ float w[128];
  __shared__ float red2[2];
  __shared__ float part[128];
  if (h < 12) {
    float s = scores[(size_t)((b * 12 + h) * 128 + i) * 128 + tid] * 0.125f
            + mask[b * 128 + tid];
    float mx = s;
#pragma unroll
    for (int o = 32; o; o >>= 1) mx = fmaxf(mx, __shfl_xor(mx, o));
    if ((tid & 63) == 0) red2[tid >> 6] = mx;
    __syncthreads();
    mx = fmaxf(red2[0], red2[1]);
    float e = __expf(s - mx);
    float sm = e;
#pragma unroll
    for (int o = 32; o; o >>= 1) sm += __shfl_xor(sm, o);
    __syncthreads();
    if ((tid & 63) == 0) red2[tid >> 6] = sm;
    __syncthreads();
    sm = red2[0] + red2[1];
    w[tid] = e / sm;
  } else {
    w[tid] = span[(size_t)(b * 128 + i) * 128 + tid];
  }
  __syncthreads();
  const float* vb = qkv + (size_t)(b * 128) * 2368 + (h < 12 ? 1536 + h * 64 : 2304);
  const int d = tid & 63, jh = tid >> 6;
  float acc = 0.f;
#pragma unroll 8
  for (int jj = 0; jj < 64; jj++) {
    int j = jh * 64 + jj;
    acc += w[j] * vb[(size_t)j * 2368 + d];
  }
  part[tid] = acc;
  __syncthreads();
  if (tid < 64)
    ctx[(size_t)(b * 128 + i) * 832 + h * 64 + tid] = part[tid] + part[tid + 64];
}

// ---------------- kernel D: out = ctx[256x832] @ Wmlp[832x768] + bmlp ----------------
__global__ __launch_bounds__(256)
void out_kernel(const float* __restrict__ ctxb, const float* __restrict__ Wmlp,
                const float* __restrict__ bmlp, float* __restrict__ out) {
  const int n0 = blockIdx.x * 32;   // 24 tiles
  const int m0 = blockIdx.y * 32;   // 8 tiles
  __shared__ float As[32][17];
  __shared__ float Bs[16][33];
  const int tid = threadIdx.x;
  const int tx = tid & 15, ty = tid >> 4;
  float acc[2][2] = {};
  for (int k0 = 0; k0 < 832; k0 += 16) {
    {
      int e = tid, row = e >> 4, kk = e & 15;
      As[row][kk] = ctxb[(m0 + row) * 832 + k0 + kk];
      e = tid + 256; row = e >> 4; kk = e & 15;
      As[row][kk] = ctxb[(m0 + row) * 832 + k0 + kk];
      e = tid; int kb = e >> 5, col = e & 31;
      Bs[kb][col] = Wmlp[(k0 + kb) * 768 + n0 + col];
      e = tid + 256; kb = e >> 5; col = e & 31;
      Bs[kb][col] = Wmlp[(k0 + kb) * 768 + n0 + col];
    }
    __syncthreads();
#pragma unroll
    for (int kk = 0; kk < 16; kk++) {
      float a0 = As[ty * 2][kk], a1 = As[ty * 2 + 1][kk];
      float b0 = Bs[kk][tx * 2], b1 = Bs[kk][tx * 2 + 1];
      acc[0][0] += a0 * b0; acc[0][1] += a0 * b1;
      acc[1][0] += a1 * b0; acc[1][1] += a1 * b1;
    }
    __syncthreads();
  }
#pragma unroll
  for (int p = 0; p < 2; p++)
#pragma unroll
    for (int q = 0; q < 2; q++)
      out[(size_t)(m0 + ty * 2 + p) * 768 + n0 + tx * 2 + q] =
          acc[p][q] + bmlp[n0 + tx * 2 + q];
}

// ---------------- launch ----------------
extern "C" void kernel_launch(void* const* d_in, const int* in_sizes, int n_in,
                              void* d_out, int out_size, void* d_ws, size_t ws_size,
                              hipStream_t stream) {
  const float* hs   = (const float*)d_in[0];
  const float* mask = (const float*)d_in[1];
  const float* infp = (const float*)d_in[2];
  const float* span = (const float*)d_in[3];
  const float* Wq   = (const float*)d_in[4];
  const float* bq   = (const float*)d_in[5];
  const float* Wk   = (const float*)d_in[6];
  const float* bk   = (const float*)d_in[7];
  const float* Wv   = (const float*)d_in[8];
  const float* bv   = (const float*)d_in[9];
  const float* Wpv  = (const float*)d_in[10];
  const float* bpv  = (const float*)d_in[11];
  const float* Wip  = (const float*)d_in[12];
  const float* Wmlp = (const float*)d_in[13];
  const float* bmlp = (const float*)d_in[14];
  float* out = (float*)d_out;

  char* ws = (char*)d_ws;
  float*  qkv    = (float*)(ws);                 // 256*2368*4   = 2424832
  __bf16* wipT   = (__bf16*)(ws + 2424832);      // 1536*768*2   = 2359296
  float*  scores = (float*)(ws + 4784128);       // 2*12*128*128*4 = 1572864
  float*  ctx    = (float*)(ws + 6356992);       // 256*832*4    = 851968
  // total ws usage: 7208960 bytes

  proj_kernel<<<dim3(74, 8), 256, 0, stream>>>(hs, Wq, bq, Wk, bk, Wv, bv, Wpv, bpv, qkv);
  wipt_kernel<<<dim3(48, 24), 256, 0, stream>>>(Wip, wipT);
  hipMemsetAsync(scores, 0, (size_t)2 * 12 * 128 * 128 * sizeof(float), stream);
  score_kernel<<<dim3(512), 256, 136192, stream>>>(infp, wipT, qkv, scores);
  attn_kernel<<<dim3(13, 128, 2), 128, 0, stream>>>(scores, qkv, mask, span, ctx);
  out_kernel<<<dim3(24, 8), 256, 0, stream>>>(ctx, Wmlp, bmlp, out);
}

// Round 2
// 417.869 us; speedup vs baseline: 2.0538x; 2.0538x over previous
//
#include <hip/hip_runtime.h>
#include <hip/hip_bf16.h>

// B=2, S=128, H=12, DH=64, HID=768
// scores(b,h,i,j) = dot64(q+ra, k+rb)/8 + mask ; ra=ip[r,64c+d], rb=ip[r,768+64c+d]
//   t = h*16384 + i*128 + j ; r = t/12, c = t%12
//   ip = inference_path @ Wip  -- 77 GFLOP bf16-MFMA GEMM, never materialized.
// score_kernel: A resident in LDS (frag-ordered bf16, 64 rows x 768k), barrier-free
// K-loop, B-frags streamed from frag-native global layout (L2) into VGPRs.

typedef __attribute__((ext_vector_type(8))) __bf16 bf16x8;
typedef __attribute__((ext_vector_type(16))) float f32x16;

// ---------------- kernel A: q/k/v/pv projections (fp32, 32x32 tiles) ----------------
__global__ __launch_bounds__(256)
void proj_kernel(const float* __restrict__ hs,
                 const float* __restrict__ Wq, const float* __restrict__ bq,
                 const float* __restrict__ Wk, const float* __restrict__ bk,
                 const float* __restrict__ Wv, const float* __restrict__ bv,
                 const float* __restrict__ Wpv, const float* __restrict__ bpv,
                 float* __restrict__ qkv) {
  const int n0 = blockIdx.x * 32;
  const int m0 = blockIdx.y * 32;
  const float* W; const float* bias; int noff, ldw;
  if (n0 < 768)       { W = Wq;  bias = bq;  noff = n0;        ldw = 768; }
  else if (n0 < 1536) { W = Wk;  bias = bk;  noff = n0 - 768;  ldw = 768; }
  else if (n0 < 2304) { W = Wv;  bias = bv;  noff = n0 - 1536; ldw = 768; }
  else                { W = Wpv; bias = bpv; noff = n0 - 2304; ldw = 64; }
  __shared__ float As[32][17];
  __shared__ float Bs[16][33];
  const int tid = threadIdx.x;
  const int tx = tid & 15, ty = tid >> 4;
  float acc[2][2] = {};
  for (int k0 = 0; k0 < 768; k0 += 16) {
    {
      int e = tid, row = e >> 4, kk = e & 15;
      As[row][kk] = hs[(m0 + row) * 768 + k0 + kk];
      e = tid + 256; row = e >> 4; kk = e & 15;
      As[row][kk] = hs[(m0 + row) * 768 + k0 + kk];
      e = tid; int kb = e >> 5, col = e & 31;
      Bs[kb][col] = W[(k0 + kb) * ldw + noff + col];
      e = tid + 256; kb = e >> 5; col = e & 31;
      Bs[kb][col] = W[(k0 + kb) * ldw + noff + col];
    }
    __syncthreads();
#pragma unroll
    for (int kk = 0; kk < 16; kk++) {
      float a0 = As[ty * 2][kk], a1 = As[ty * 2 + 1][kk];
      float b0 = Bs[kk][tx * 2], b1 = Bs[kk][tx * 2 + 1];
      acc[0][0] += a0 * b0; acc[0][1] += a0 * b1;
      acc[1][0] += a1 * b0; acc[1][1] += a1 * b1;
    }
    __syncthreads();
  }
#pragma unroll
  for (int p = 0; p < 2; p++)
#pragma unroll
    for (int q = 0; q < 2; q++)
      qkv[(size_t)(m0 + ty * 2 + p) * 2368 + n0 + tx * 2 + q] =
          acc[p][q] + bias[noff + tx * 2 + q];
}

// ---------------- kernel T: Wip fp32 [768][1536] -> fragment-native bf16 ----------------
// layout: frag block 1KB at index ((c*12+kc)*16 + f), f = ks*4 + half*2 + nt
//   lane l holds 8 bf16: col = half*768 + c*64 + nt*32 + (l&31),
//                         k  = kc*64 + ks*16 + (l>>5)*8 + j
__global__ __launch_bounds__(256)
void wip_frag_kernel(const float* __restrict__ Wip, __bf16* __restrict__ wf) {
  __shared__ float lds_w[64 * 132];
  const int c = blockIdx.x;    // 0..11
  const int kc = blockIdx.y;   // 0..11
  const int tid = threadIdx.x;
  for (int e = tid; e < 8192; e += 256) {
    int row = e >> 7, col = e & 127;
    int gcol = ((col >> 6) * 768) + c * 64 + (col & 63);
    lds_w[row * 132 + col] = Wip[(size_t)(kc * 64 + row) * 1536 + gcol];
  }
  __syncthreads();
  for (int s = tid; s < 1024; s += 256) {
    int f = s >> 6, l = s & 63;
    int ks = f >> 2, half = (f >> 1) & 1, nt = f & 1;
    int col_local = half * 64 + nt * 32 + (l & 31);
    int kb = ks * 16 + (l >> 5) * 8;
    union { __bf16 h[8]; uint4 u; } pk;
#pragma unroll
    for (int j = 0; j < 8; j++)
      pk.h[j] = (__bf16)lds_w[(kb + j) * 132 + col_local];
    ((uint4*)wf)[(size_t)((c * 12 + kc) * 16 + f) * 64 + l] = pk.u;
  }
}

// ---------------- kernel B: fused ip-GEMM + score reduction ----------------
// 512 blocks (b x 256 row-groups of 64) x 512 thr (8 waves).
// Wave (wc 0..3, wd 0..1): c in {wc, wc+4, wc+8}, d-half wd, all 64 rows.
// A: LDS frag-ordered bf16, frag stride 1040B (96 frags). Barrier-free K-loop.
extern __shared__ char smem_raw[];

__global__ __launch_bounds__(512, 2)
void score_kernel(const float* __restrict__ infp,
                  const __bf16* __restrict__ wf,
                  const float* __restrict__ qkv,
                  float* __restrict__ scores) {
  char* Abase = smem_raw;                        // 96 frags * 1040 = 99840 B
  float* lds_sc = (float*)(smem_raw + 99840);    // 64*12 floats = 3072 B
  const int tid = threadIdx.x;
  const int lane = tid & 63;
  const int ml = lane & 31;
  const int kh = lane >> 5;
  const int wv = tid >> 6;       // 0..7
  const int wc = wv & 3;
  const int wd = wv >> 2;
  const int blk = blockIdx.x;
  const int b = blk >> 8;
  const int r0 = (blk & 255) << 6;

  for (int z = tid; z < 768; z += 512) lds_sc[z] = 0.f;

  // ---- stage A: 64 rows x 768 fp32 -> bf16 frag-ordered LDS (coalesced reads)
  {
    const float4* A4 = (const float4*)(infp + (size_t)(b * 16384 + r0) * 768);
#pragma unroll
    for (int p = 0; p < 12; p++) {
      int idx = p * 512 + tid;                // granule index 0..6143
      int m = (int)(((unsigned)idx * 10923u) >> 20);   // idx/96
      int g = idx - m * 96;
      float4 v0 = A4[m * 192 + g * 2];
      float4 v1 = A4[m * 192 + g * 2 + 1];
      union { __bf16 h[8]; uint4 u; } pk;
      pk.h[0] = (__bf16)v0.x; pk.h[1] = (__bf16)v0.y;
      pk.h[2] = (__bf16)v0.z; pk.h[3] = (__bf16)v0.w;
      pk.h[4] = (__bf16)v1.x; pk.h[5] = (__bf16)v1.y;
      pk.h[6] = (__bf16)v1.z; pk.h[7] = (__bf16)v1.w;
      int F = (m >> 5) * 48 + (g >> 1);
      int slot = (m & 31) + ((g & 1) << 5);
      *(uint4*)(Abase + ((F * 65 + slot) << 4)) = pk.u;
    }
  }
  __syncthreads();

  // ---- barrier-free main loop: 3 c-values x 12 kc chunks
  const size_t lane_off = (size_t)(lane << 4);
  uint4 Bcur[8], Bnxt[8];
  auto loadB = [&](uint4* dst, int c, int kc) {
    const char* base = (const char*)wf + (size_t)((c * 12 + kc) << 14) + (wd << 10) + lane_off;
#pragma unroll
    for (int ks = 0; ks < 4; ks++) {
      dst[ks * 2]     = *(const uint4*)(base + ks * 4096);          // ra (half=0)
      dst[ks * 2 + 1] = *(const uint4*)(base + ks * 4096 + 2048);   // rb (half=1)
    }
  };

  int c = wc;
  loadB(Bcur, c, 0);
  f32x16 acc_ra[2], acc_rb[2];
#pragma unroll
  for (int mt = 0; mt < 2; mt++)
#pragma unroll
    for (int z = 0; z < 16; z++) { acc_ra[mt][z] = 0.f; acc_rb[mt][z] = 0.f; }

  for (int it = 0; it < 36; it++) {
    int kc = it - (it >= 12 ? (it >= 24 ? 24 : 12) : 0);
    // prefetch next iteration's B
    if (it < 35) {
      int nit = it + 1;
      int nkc = nit - (nit >= 12 ? (nit >= 24 ? 24 : 12) : 0);
      int nc = wc + (nit / 12) * 4;
      loadB(Bnxt, nc, nkc);
    }
    // A fragments for this kc (8 x ds_read_b128, lane-linear, conflict-free)
    bf16x8 af[2][4];
#pragma unroll
    for (int mt = 0; mt < 2; mt++)
#pragma unroll
      for (int ks = 0; ks < 4; ks++)
        af[mt][ks] = *(const bf16x8*)(Abase + (((mt * 48 + kc * 4 + ks) * 65) << 4) + lane_off);
#pragma unroll
    for (int ks = 0; ks < 4; ks++) {
      bf16x8 bra = *(const bf16x8*)&Bcur[ks * 2];
      bf16x8 brb = *(const bf16x8*)&Bcur[ks * 2 + 1];
#pragma unroll
      for (int mt = 0; mt < 2; mt++) {
        acc_ra[mt] = __builtin_amdgcn_mfma_f32_32x32x16_bf16(af[mt][ks], bra, acc_ra[mt], 0, 0, 0);
        acc_rb[mt] = __builtin_amdgcn_mfma_f32_32x32x16_bf16(af[mt][ks], brb, acc_rb[mt], 0, 0, 0);
      }
    }
#pragma unroll
    for (int z = 0; z < 8; z++) Bcur[z] = Bnxt[z];

    if (kc == 11) {
      // ---- epilogue for this c: (q+ra)(k+rb), reduce over 32 d-lanes, LDS-atomic
      int d = wd * 32 + ml;
#pragma unroll
      for (int mt = 0; mt < 2; mt++) {
#pragma unroll
        for (int reg = 0; reg < 16; reg++) {
          int row = mt * 32 + (reg & 3) + ((reg >> 2) << 3) + (kh << 2);
          int t = 12 * (r0 + row) + c;
          int hh = t >> 14;
          int ii = (t >> 7) & 127;
          int jj = t & 127;
          float qv = qkv[(size_t)((b << 7) + ii) * 2368 + (hh << 6) + d];
          float kv = qkv[(size_t)((b << 7) + jj) * 2368 + 768 + (hh << 6) + d];
          float p = (qv + acc_ra[mt][reg]) * (kv + acc_rb[mt][reg]);
          p += __shfl_xor(p, 16);
          p += __shfl_xor(p, 8);
          p += __shfl_xor(p, 4);
          p += __shfl_xor(p, 2);
          p += __shfl_xor(p, 1);
          if (ml == 0) atomicAdd(&lds_sc[row * 12 + c], p);
        }
      }
      c += 4;
#pragma unroll
      for (int mt = 0; mt < 2; mt++)
#pragma unroll
        for (int z = 0; z < 16; z++) { acc_ra[mt][z] = 0.f; acc_rb[mt][z] = 0.f; }
    }
  }

  __syncthreads();
  for (int z = tid; z < 768; z += 512) {
    int row = z / 12;
    int cc = z - row * 12;
    int t = 12 * (r0 + row) + cc;
    int hh = t >> 14;
    int ii = (t >> 7) & 127;
    int jj = t & 127;
    scores[(size_t)((b * 12 + hh) * 128 + ii) * 128 + jj] = lds_sc[z];
  }
}

// ---------------- kernel C: softmax + probs@v (+ parse path as head 12) ----------------
__global__ __launch_bounds__(128)
void attn_kernel(const float* __restrict__ scores, const float* __restrict__ qkv,
                 const float* __restrict__ mask, const float* __restrict__ span,
                 float* __restrict__ ctx) {
  const int h = blockIdx.x;   // 0..12 (12 = parse path)
  const int i = blockIdx.y;
  const int b = blockIdx.z;
  const int tid = threadIdx.x;
  __shared__ float w[128];
  __shared__ float red2[2];
  __shared__ float part[128];
  if (h < 12) {
    float s = scores[(size_t)((b * 12 + h) * 128 + i) * 128 + tid] * 0.125f
            + mask[b * 128 + tid];
    float mx = s;
#pragma unroll
    for (int o = 32; o; o >>= 1) mx = fmaxf(mx, __shfl_xor(mx, o));
    if ((tid & 63) == 0) red2[tid >> 6] = mx;
    __syncthreads();
    mx = fmaxf(red2[0], red2[1]);
    float e = __expf(s - mx);
    float sm = e;
#pragma unroll
    for (int o = 32; o; o >>= 1) sm += __shfl_xor(sm, o);
    __syncthreads();
    if ((tid & 63) == 0) red2[tid >> 6] = sm;
    __syncthreads();
    sm = red2[0] + red2[1];
    w[tid] = e / sm;
  } else {
    w[tid] = span[(size_t)(b * 128 + i) * 128 + tid];
  }
  __syncthreads();
  const float* vb = qkv + (size_t)(b * 128) * 2368 + (h < 12 ? 1536 + h * 64 : 2304);
  const int d = tid & 63, jh = tid >> 6;
  float acc = 0.f;
#pragma unroll 8
  for (int jj = 0; jj < 64; jj++) {
    int j = jh * 64 + jj;
    acc += w[j] * vb[(size_t)j * 2368 + d];
  }
  part[tid] = acc;
  __syncthreads();
  if (tid < 64)
    ctx[(size_t)(b * 128 + i) * 832 + h * 64 + tid] = part[tid] + part[tid + 64];
}

// ---------------- kernel D: out = ctx[256x832] @ Wmlp[832x768] + bmlp ----------------
__global__ __launch_bounds__(256)
void out_kernel(const float* __restrict__ ctxb, const float* __restrict__ Wmlp,
                const float* __restrict__ bmlp, float* __restrict__ out) {
  const int n0 = blockIdx.x * 32;
  const int m0 = blockIdx.y * 32;
  __shared__ float As[32][17];
  __shared__ float Bs[16][33];
  const int tid = threadIdx.x;
  const int tx = tid & 15, ty = tid >> 4;
  float acc[2][2] = {};
  for (int k0 = 0; k0 < 832; k0 += 16) {
    {
      int e = tid, row = e >> 4, kk = e & 15;
      As[row][kk] = ctxb[(m0 + row) * 832 + k0 + kk];
      e = tid + 256; row = e >> 4; kk = e & 15;
      As[row][kk] = ctxb[(m0 + row) * 832 + k0 + kk];
      e = tid; int kb = e >> 5, col = e & 31;
      Bs[kb][col] = Wmlp[(k0 + kb) * 768 + n0 + col];
      e = tid + 256; kb = e >> 5; col = e & 31;
      Bs[kb][col] = Wmlp[(k0 + kb) * 768 + n0 + col];
    }
    __syncthreads();
#pragma unroll
    for (int kk = 0; kk < 16; kk++) {
      float a0 = As[ty * 2][kk], a1 = As[ty * 2 + 1][kk];
      float b0 = Bs[kk][tx * 2], b1 = Bs[kk][tx * 2 + 1];
      acc[0][0] += a0 * b0; acc[0][1] += a0 * b1;
      acc[1][0] += a1 * b0; acc[1][1] += a1 * b1;
    }
    __syncthreads();
  }
#pragma unroll
  for (int p = 0; p < 2; p++)
#pragma unroll
    for (int q = 0; q < 2; q++)
      out[(size_t)(m0 + ty * 2 + p) * 768 + n0 + tx * 2 + q] =
          acc[p][q] + bmlp[n0 + tx * 2 + q];
}

// ---------------- launch ----------------
extern "C" void kernel_launch(void* const* d_in, const int* in_sizes, int n_in,
                              void* d_out, int out_size, void* d_ws, size_t ws_size,
                              hipStream_t stream) {
  const float* hs   = (const float*)d_in[0];
  const float* mask = (const float*)d_in[1];
  const float* infp = (const float*)d_in[2];
  const float* span = (const float*)d_in[3];
  const float* Wq   = (const float*)d_in[4];
  const float* bq   = (const float*)d_in[5];
  const float* Wk   = (const float*)d_in[6];
  const float* bk   = (const float*)d_in[7];
  const float* Wv   = (const float*)d_in[8];
  const float* bv   = (const float*)d_in[9];
  const float* Wpv  = (const float*)d_in[10];
  const float* bpv  = (const float*)d_in[11];
  const float* Wip  = (const float*)d_in[12];
  const float* Wmlp = (const float*)d_in[13];
  const float* bmlp = (const float*)d_in[14];
  float* out = (float*)d_out;

  char* ws = (char*)d_ws;
  float*  qkv    = (float*)(ws);                 // 256*2368*4   = 2424832
  __bf16* wfrag  = (__bf16*)(ws + 2424832);      // 12*12*16*1024 = 2359296
  float*  scores = (float*)(ws + 4784128);       // 2*12*128*128*4 = 1572864
  float*  ctx    = (float*)(ws + 6356992);       // 256*832*4    = 851968
  // total ws usage: 7208960 bytes

  proj_kernel<<<dim3(74, 8), 256, 0, stream>>>(hs, Wq, bq, Wk, bk, Wv, bv, Wpv, bpv, qkv);
  wip_frag_kernel<<<dim3(12, 12), 256, 0, stream>>>(Wip, wfrag);
  score_kernel<<<dim3(512), 512, 102912, stream>>>(infp, wfrag, qkv, scores);
  attn_kernel<<<dim3(13, 128, 2), 128, 0, stream>>>(scores, qkv, mask, span, ctx);
  out_kernel<<<dim3(24, 8), 256, 0, stream>>>(ctx, Wmlp, bmlp, out);
}